// Round 4
// baseline (4963.228 us; speedup 1.0000x reference)
//
#include <hip/hip_runtime.h>
#include <hip/hip_bf16.h>
#include <stdint.h>

#define B_    64
#define T_    1024
#define DIN   136
#define DINP  160
#define H_    256
#define G4H   1024

typedef __bf16 bf16;
typedef __bf16 bf16x8 __attribute__((ext_vector_type(8)));
typedef float  floatx4 __attribute__((ext_vector_type(4)));
typedef int    int4v  __attribute__((ext_vector_type(4)));

// ---------------- pack kernels (validated R1/R2) ----------------
__global__ void k_pack_x(const float* __restrict__ x, bf16* __restrict__ xp) {
  const int n = T_ * B_ * DINP;
  for (int i = blockIdx.x * blockDim.x + threadIdx.x; i < n; i += gridDim.x * blockDim.x) {
    int k  = i % DINP;
    int tb = i / DINP;
    int b  = tb % B_;
    int t  = tb / B_;
    float v = 0.f;
    if (k < DIN) v = x[(b * T_ + t) * DIN + k];
    xp[i] = (bf16)v;   // layout [t][b][k], k zero-padded to 160
  }
}

// packed row r = 4*hid + gate  ->  orig row = gate*256 + hid
__global__ void k_pack_whh(const float* __restrict__ wf, const float* __restrict__ wb,
                           bf16* __restrict__ wp) {
  const int n = 2 * G4H * H_;
  for (int i = blockIdx.x * blockDim.x + threadIdx.x; i < n; i += gridDim.x * blockDim.x) {
    int k   = i & (H_ - 1);
    int r   = (i >> 8) & (G4H - 1);
    int dir = i >> 18;
    int orig = ((r & 3) << 8) | (r >> 2);
    const float* w = dir ? wb : wf;
    wp[i] = (bf16)w[orig * H_ + k];
  }
}

__global__ void k_pack_wih(const float* __restrict__ wf, const float* __restrict__ wb,
                           bf16* __restrict__ wp) {
  const int n = 2 * G4H * DINP;
  for (int i = blockIdx.x * blockDim.x + threadIdx.x; i < n; i += gridDim.x * blockDim.x) {
    int k   = i % DINP;
    int r   = (i / DINP) & (G4H - 1);
    int dir = i / (G4H * DINP);
    int orig = ((r & 3) << 8) | (r >> 2);
    const float* w = dir ? wb : wf;
    float v = (k < DIN) ? w[orig * DIN + k] : 0.f;
    wp[i] = (bf16)v;
  }
}

__global__ void k_pack_bias(const float* __restrict__ bihf, const float* __restrict__ bhhf,
                            const float* __restrict__ bihb, const float* __restrict__ bhhb,
                            float* __restrict__ bs) {
  int i = blockIdx.x * blockDim.x + threadIdx.x;
  if (i >= 2 * G4H) return;
  int r = i & (G4H - 1); int dir = i >> 10;
  int orig = ((r & 3) << 8) | (r >> 2);
  bs[i] = dir ? (bihb[orig] + bhhb[orig]) : (bihf[orig] + bhhf[orig]);
}

// ---------------- persistent LSTM: tagged-data exchange, no flags/drains ----------------
// wave = (dir 2) x (btile 4) x (qtr 4) x (w 4): owns 16 hid x 16 batch.
// Publish: dword per element = (t<<16) | bf16(h) into 4-deep ring (sc1 stores).
// Consume: bulk-load 16x dwordx4 (sc0 sc1), validate all tags == t-1, retry.
// The load IS the sync: no vmcnt drain, no flag, no poll RTTs.
__global__ __launch_bounds__(256, 1) void k_lstm(
    const bf16* __restrict__ xp, const bf16* __restrict__ whhp,
    const bf16* __restrict__ wihp, const float* __restrict__ bs,
    bf16* __restrict__ hseq, unsigned* __restrict__ ring)
{
  const int tid = threadIdx.x;
  const int w   = tid >> 6;        // wave within wg 0..3
  const int l   = tid & 63;
  const int q   = l >> 4;
  const int m   = l & 15;

  const int wgid  = blockIdx.x;    // 0..31
  const int g     = wgid >> 2;     // dir*4 + btile
  const int qtr   = wgid & 3;
  const int dir   = g >> 2;
  const int btile = g & 3;
  const int rowbase = qtr * 256 + w * 64;   // packed gate-row base for this wave

  // ---- weight fragments into registers ----
  bf16x8 wf[4][8];      // Whh
  bf16x8 wif[4][5];     // Wih
  floatx4 bias[4];
#pragma unroll
  for (int tl = 0; tl < 4; ++tl) {
    const bf16* wr = whhp + (size_t)(dir * G4H + rowbase + tl * 16 + m) * H_ + q * 8;
#pragma unroll
    for (int c = 0; c < 8; ++c) wf[tl][c] = *(const bf16x8*)(wr + c * 32);
    const bf16* wr2 = wihp + (size_t)(dir * G4H + rowbase + tl * 16 + m) * DINP + q * 8;
#pragma unroll
    for (int c = 0; c < 5; ++c) wif[tl][c] = *(const bf16x8*)(wr2 + c * 32);
    bias[tl] = *(const floatx4*)(bs + dir * G4H + rowbase + tl * 16 + q * 4);
  }

  unsigned* const hseq_dw = (unsigned*)hseq;
  const size_t hb_g = (size_t)g * T_;

  float cst[4] = {0.f, 0.f, 0.f, 0.f};

  bf16x8 xf[5];
  {
    const int xt0 = dir ? (T_ - 1) : 0;
    const bf16* xr = xp + (size_t)(xt0 * B_ + btile * 16 + m) * DINP + q * 8;
#pragma unroll
    for (int c = 0; c < 5; ++c) xf[c] = *(const bf16x8*)(xr + c * 32);
  }

  for (int t = 0; t < T_; ++t) {
    const int xt = dir ? (T_ - 1 - t) : t;
    floatx4 acc[4] = {bias[0], bias[1], bias[2], bias[3]};

    // input projection (independent of h)
#pragma unroll
    for (int c = 0; c < 5; ++c) {
#pragma unroll
      for (int tl = 0; tl < 4; ++tl)
        acc[tl] = __builtin_amdgcn_mfma_f32_16x16x32_bf16(wif[tl][c], xf[c], acc[tl], 0, 0, 0);
    }
    // prefetch next step's x
    if (t + 1 < T_) {
      const int xtn = dir ? (T_ - 2 - t) : (t + 1);
      const bf16* xr = xp + (size_t)(xtn * B_ + btile * 16 + m) * DINP + q * 8;
#pragma unroll
      for (int c = 0; c < 5; ++c) xf[c] = *(const bf16x8*)(xr + c * 32);
    }

    if (t > 0) {
      // validated bulk load of h(t-1): ring page [(t-1)&3][g], row m, dword hid
      const unsigned* p = ring + ((size_t)(((t - 1) & 3) * 8 + g) * 16 + m) * 256 + (q << 3);
      const unsigned exp = ((unsigned)(t - 1)) << 16;
      bf16x8 hfr[8];
      for (;;) {
        int4v d0, d1, d2, d3, d4, d5, d6, d7, d8, d9, d10, d11, d12, d13, d14, d15;
        asm volatile(
          "global_load_dwordx4 %0, %[a], off sc0 sc1\n\t"
          "global_load_dwordx4 %1, %[a], off offset:16 sc0 sc1\n\t"
          "global_load_dwordx4 %2, %[a], off offset:128 sc0 sc1\n\t"
          "global_load_dwordx4 %3, %[a], off offset:144 sc0 sc1\n\t"
          "global_load_dwordx4 %4, %[a], off offset:256 sc0 sc1\n\t"
          "global_load_dwordx4 %5, %[a], off offset:272 sc0 sc1\n\t"
          "global_load_dwordx4 %6, %[a], off offset:384 sc0 sc1\n\t"
          "global_load_dwordx4 %7, %[a], off offset:400 sc0 sc1\n\t"
          "global_load_dwordx4 %8, %[a], off offset:512 sc0 sc1\n\t"
          "global_load_dwordx4 %9, %[a], off offset:528 sc0 sc1\n\t"
          "global_load_dwordx4 %10, %[a], off offset:640 sc0 sc1\n\t"
          "global_load_dwordx4 %11, %[a], off offset:656 sc0 sc1\n\t"
          "global_load_dwordx4 %12, %[a], off offset:768 sc0 sc1\n\t"
          "global_load_dwordx4 %13, %[a], off offset:784 sc0 sc1\n\t"
          "global_load_dwordx4 %14, %[a], off offset:896 sc0 sc1\n\t"
          "global_load_dwordx4 %15, %[a], off offset:912 sc0 sc1\n\t"
          "s_waitcnt vmcnt(0)"
          : "=v"(d0), "=v"(d1), "=v"(d2), "=v"(d3), "=v"(d4), "=v"(d5), "=v"(d6), "=v"(d7),
            "=v"(d8), "=v"(d9), "=v"(d10), "=v"(d11), "=v"(d12), "=v"(d13), "=v"(d14), "=v"(d15)
          : [a] "v"(p)
          : "memory");

        unsigned dev = 0;
        int4v lo, hi;
#define PACK_CHUNK(cc, L, Hh)                                                   \
        lo = L; hi = Hh;                                                        \
        dev |= (lo[0] ^ exp) | (lo[1] ^ exp) | (lo[2] ^ exp) | (lo[3] ^ exp)    \
             | (hi[0] ^ exp) | (hi[1] ^ exp) | (hi[2] ^ exp) | (hi[3] ^ exp);   \
        {                                                                       \
          int4v fr;                                                             \
          fr[0] = (int)((lo[0] & 0xFFFFu) | ((unsigned)lo[1] << 16));           \
          fr[1] = (int)((lo[2] & 0xFFFFu) | ((unsigned)lo[3] << 16));           \
          fr[2] = (int)((hi[0] & 0xFFFFu) | ((unsigned)hi[1] << 16));           \
          fr[3] = (int)((hi[2] & 0xFFFFu) | ((unsigned)hi[3] << 16));           \
          hfr[cc] = __builtin_bit_cast(bf16x8, fr);                             \
        }
        PACK_CHUNK(0, d0,  d1)
        PACK_CHUNK(1, d2,  d3)
        PACK_CHUNK(2, d4,  d5)
        PACK_CHUNK(3, d6,  d7)
        PACK_CHUNK(4, d8,  d9)
        PACK_CHUNK(5, d10, d11)
        PACK_CHUNK(6, d12, d13)
        PACK_CHUNK(7, d14, d15)
#undef PACK_CHUNK
        if (__all((int)((dev & 0xFFFF0000u) == 0u))) break;
      }

#pragma unroll
      for (int c = 0; c < 8; ++c) {
#pragma unroll
        for (int tl = 0; tl < 4; ++tl)
          acc[tl] = __builtin_amdgcn_mfma_f32_16x16x32_bf16(wf[tl][c], hfr[c], acc[tl], 0, 0, 0);
      }
    }

    // in-lane cell update: reg0=i reg1=f reg2=g reg3=o for (hid = qtr*64+w*16+tl*4+q, b = btile*16+m)
    unsigned short hu[4];
#pragma unroll
    for (int tl = 0; tl < 4; ++tl) {
      float pi = acc[tl][0], pf = acc[tl][1], pg = acc[tl][2], po = acc[tl][3];
      float ig = 1.f / (1.f + __expf(-pi));
      float fg = 1.f / (1.f + __expf(-pf));
      float og = 1.f / (1.f + __expf(-po));
      float gcl = fminf(fmaxf(pg, -15.f), 15.f);
      float e2  = __expf(2.f * gcl);
      float gg  = (e2 - 1.f) / (e2 + 1.f);
      float c   = fg * cst[tl] + ig * gg;
      cst[tl]   = c;
      float ccl = fminf(fmaxf(c, -15.f), 15.f);
      float ec  = __expf(2.f * ccl);
      float hv  = og * ((ec - 1.f) / (ec + 1.f));
      bf16 hb = (bf16)hv;
      hu[tl] = __builtin_bit_cast(unsigned short, hb);
    }

    // publish tagged dwords into ring page [t&3][g]: element (m, hid)
    {
      const unsigned tagv = ((unsigned)t) << 16;
      unsigned* pg = ring + ((size_t)((t & 3) * 8 + g) * 16 + m) * 256
                   + (size_t)(qtr * 64 + w * 16 + q);
#pragma unroll
      for (int tl = 0; tl < 4; ++tl)
        __hip_atomic_store(pg + tl * 4, tagv | (unsigned)hu[tl],
                           __ATOMIC_RELAXED, __HIP_MEMORY_SCOPE_AGENT);
    }

    // plain cached bf16 stores for k_fc (visible at kernel boundary)
    {
      const size_t obase = ((hb_g + xt) * 16 + m) * 128 + (size_t)(qtr * 32 + w * 8);
#pragma unroll
      for (int tl = 0; tl < 4; ++tl) {
        int ov = __shfl_xor((int)(unsigned)hu[tl], 16);
        if ((q & 1) == 0) {
          unsigned dw = (unsigned)hu[tl] | ((unsigned)ov << 16);
          hseq_dw[obase + tl * 2 + (q >> 1)] = dw;
        }
      }
    }
  }
}

// ---------------- FC epilogue ----------------
// one block per t; hseq layout [g=dir*4+btile][xt][m][hid 256] bf16
__global__ __launch_bounds__(512) void k_fc(const bf16* __restrict__ hbuf,
                                            const float* __restrict__ fcw,
                                            const float* __restrict__ fcb,
                                            float* __restrict__ out)
{
  __shared__ float wsm[5 * 512];
  __shared__ unsigned short hl[64 * 258];      // [b][hid 256 pad 258]
  const int tid = threadIdx.x;
  const int t   = blockIdx.x;
  for (int i = tid; i < 2560; i += 512) wsm[i] = fcw[i];
  const int o = tid / 64, b = tid & 63;
  float acc = 0.f;
  for (int dirc = 0; dirc < 2; ++dirc) {
    __syncthreads();
    for (int i = tid; i < 8192; i += 512) {
      int bb = i >> 7, dd = i & 127;
      int gg = dirc * 4 + (bb >> 4), mm = bb & 15;
      ((unsigned*)hl)[bb * 129 + dd] =
          ((const unsigned*)hbuf)[((size_t)(gg * T_ + t) * 16 + mm) * 128 + dd];
    }
    __syncthreads();
    if (tid < 320) {
      const float* wr = &wsm[o * 512 + dirc * 256];
      const unsigned short* hr = &hl[b * 258];
      float a = 0.f;
#pragma unroll 8
      for (int h = 0; h < 256; ++h) {
        unsigned u = ((unsigned)hr[h]) << 16;
        a += wr[h] * __builtin_bit_cast(float, u);
      }
      acc += a;
    }
  }
  if (tid < 320) out[((size_t)b * T_ + t) * 5 + o] = acc + fcb[o];
}

// ---------------- launcher ----------------
extern "C" void kernel_launch(void* const* d_in, const int* in_sizes, int n_in,
                              void* d_out, int out_size, void* d_ws, size_t ws_size,
                              hipStream_t stream) {
  const float* x    = (const float*)d_in[0];
  const float* wihf = (const float*)d_in[1];
  const float* whhf = (const float*)d_in[2];
  const float* bihf = (const float*)d_in[3];
  const float* bhhf = (const float*)d_in[4];
  const float* wihb = (const float*)d_in[5];
  const float* whhb = (const float*)d_in[6];
  const float* bihb = (const float*)d_in[7];
  const float* bhhb = (const float*)d_in[8];
  const float* fcw  = (const float*)d_in[9];
  const float* fcb  = (const float*)d_in[10];
  float* out = (float*)d_out;

  char* ws = (char*)d_ws;
  bf16*     xp   = (bf16*)(ws + 0);            // 20,971,520 B
  bf16*     whhp = (bf16*)(ws + 20971520);     //  1,048,576 B
  bf16*     wihp = (bf16*)(ws + 22020096);     //    655,360 B
  float*    bsum = (float*)(ws + 22675456);    //      8,192 B
  unsigned* ring = (unsigned*)(ws + 22683648); //    524,288 B (poison tag 0xAAAA != any t)
  bf16*     hseq = (bf16*)(ws + 23207936);     // 67,108,864 B  [g][xt][m][hid]
  (void)in_sizes; (void)n_in; (void)out_size; (void)ws_size;

  k_pack_x   <<<4096, 256, 0, stream>>>(x, xp);
  k_pack_whh <<<1024, 256, 0, stream>>>(whhf, whhb, whhp);
  k_pack_wih <<<640,  256, 0, stream>>>(wihf, wihb, wihp);
  k_pack_bias<<<8,    256, 0, stream>>>(bihf, bhhf, bihb, bhhb, bsum);
  k_lstm     <<<32,   256, 0, stream>>>(xp, whhp, wihp, bsum, hseq, ring);
  k_fc       <<<1024, 512, 0, stream>>>(hseq, fcw, fcb, out);
}

// Round 5
// 2707.891 us; speedup vs baseline: 1.8329x; 1.8329x over previous
//
#include <hip/hip_runtime.h>
#include <hip/hip_bf16.h>
#include <stdint.h>

#define B_    64
#define T_    1024
#define DIN   136
#define DINP  160
#define H_    256
#define G4H   1024

typedef __bf16 bf16;
typedef __bf16 bf16x8 __attribute__((ext_vector_type(8)));
typedef float  floatx4 __attribute__((ext_vector_type(4)));
typedef int    int4v  __attribute__((ext_vector_type(4)));

// ---------------- pack kernels (validated R1/R2) ----------------
__global__ void k_pack_x(const float* __restrict__ x, bf16* __restrict__ xp) {
  const int n = T_ * B_ * DINP;
  for (int i = blockIdx.x * blockDim.x + threadIdx.x; i < n; i += gridDim.x * blockDim.x) {
    int k  = i % DINP;
    int tb = i / DINP;
    int b  = tb % B_;
    int t  = tb / B_;
    float v = 0.f;
    if (k < DIN) v = x[(b * T_ + t) * DIN + k];
    xp[i] = (bf16)v;   // layout [t][b][k], k zero-padded to 160
  }
}

// packed row r = 4*hid + gate  ->  orig row = gate*256 + hid
__global__ void k_pack_whh(const float* __restrict__ wf, const float* __restrict__ wb,
                           bf16* __restrict__ wp) {
  const int n = 2 * G4H * H_;
  for (int i = blockIdx.x * blockDim.x + threadIdx.x; i < n; i += gridDim.x * blockDim.x) {
    int k   = i & (H_ - 1);
    int r   = (i >> 8) & (G4H - 1);
    int dir = i >> 18;
    int orig = ((r & 3) << 8) | (r >> 2);
    const float* w = dir ? wb : wf;
    wp[i] = (bf16)w[orig * H_ + k];
  }
}

__global__ void k_pack_wih(const float* __restrict__ wf, const float* __restrict__ wb,
                           bf16* __restrict__ wp) {
  const int n = 2 * G4H * DINP;
  for (int i = blockIdx.x * blockDim.x + threadIdx.x; i < n; i += gridDim.x * blockDim.x) {
    int k   = i % DINP;
    int r   = (i / DINP) & (G4H - 1);
    int dir = i / (G4H * DINP);
    int orig = ((r & 3) << 8) | (r >> 2);
    const float* w = dir ? wb : wf;
    float v = (k < DIN) ? w[orig * DIN + k] : 0.f;
    wp[i] = (bf16)v;
  }
}

__global__ void k_pack_bias(const float* __restrict__ bihf, const float* __restrict__ bhhf,
                            const float* __restrict__ bihb, const float* __restrict__ bhhb,
                            float* __restrict__ bs) {
  int i = blockIdx.x * blockDim.x + threadIdx.x;
  if (i >= 2 * G4H) return;
  int r = i & (G4H - 1); int dir = i >> 10;
  int orig = ((r & 3) << 8) | (r >> 2);
  bs[i] = dir ? (bihb[orig] + bhhb[orig]) : (bihf[orig] + bhhf[orig]);
}

// ---------------- persistent LSTM: tagged exchange + cooperative LDS staging ----------------
// 32 wgs x 256 thr (R2 shape: weights fully in registers, 1 wave/SIMD).
// Group = (dir, btile) = 4 wgs (qtr 0..3). Wave owns 16 hid x 16 batch.
// Publish: ONE tagged dwordx4 sc0 sc1 store per lane (tag=t in high halves), 4-deep ring.
// Consume: 3 dwordx4 per lane per attempt (partner quarters, cooperative), validate 12 tags,
// s_sleep(1) backoff, unscramble to double-buffered LDS, ONE __syncthreads per step.
// No vmcnt drains, no flags, no cache fences — the validated load IS the sync.
__global__ __launch_bounds__(256, 1) void k_lstm(
    const bf16* __restrict__ xp, const bf16* __restrict__ whhp,
    const bf16* __restrict__ wihp, const float* __restrict__ bs,
    bf16* __restrict__ hseq, unsigned* __restrict__ ring)
{
  __shared__ unsigned short h_su[2 * 16 * 264];   // [parity][m 16][hid 256 pad 264]

  const int tid = threadIdx.x;
  const int w   = tid >> 6;        // wave 0..3
  const int l   = tid & 63;
  const int q   = l >> 4;
  const int m   = l & 15;

  const int wgid  = blockIdx.x;    // 0..31
  const int g     = wgid >> 2;     // dir*4 + btile
  const int qtr   = wgid & 3;
  const int dir   = g >> 2;
  const int btile = g & 3;
  const int rowbase = qtr * 256 + w * 64;   // packed gate-row base for this wave

  // ---- weight fragments into registers ----
  bf16x8 wf[4][8];      // Whh
  bf16x8 wif[4][5];     // Wih
  floatx4 bias[4];
#pragma unroll
  for (int tl = 0; tl < 4; ++tl) {
    const bf16* wr = whhp + (size_t)(dir * G4H + rowbase + tl * 16 + m) * H_ + q * 8;
#pragma unroll
    for (int c = 0; c < 8; ++c) wf[tl][c] = *(const bf16x8*)(wr + c * 32);
    const bf16* wr2 = wihp + (size_t)(dir * G4H + rowbase + tl * 16 + m) * DINP + q * 8;
#pragma unroll
    for (int c = 0; c < 5; ++c) wif[tl][c] = *(const bf16x8*)(wr2 + c * 32);
    bias[tl] = *(const floatx4*)(bs + dir * G4H + rowbase + tl * 16 + q * 4);
  }

  unsigned* const hseq_dw = (unsigned*)hseq;
  const size_t hb_g = (size_t)g * T_;

  // staging assignment (wg-cooperative): tid -> (mm, j4) within each partner quarter
  const int mm = tid >> 4;
  const int j4 = (tid & 15) << 2;
  const int hid0 = (j4 & 48) + ((j4 >> 2) & 3);   // unscrambled hid base (stride 4 over i)

  float cst[4] = {0.f, 0.f, 0.f, 0.f};

  bf16x8 xf[5];
  {
    const int xt0 = dir ? (T_ - 1) : 0;
    const bf16* xr = xp + (size_t)(xt0 * B_ + btile * 16 + m) * DINP + q * 8;
#pragma unroll
    for (int c = 0; c < 5; ++c) xf[c] = *(const bf16x8*)(xr + c * 32);
  }

  for (int t = 0; t < T_; ++t) {
    const int xt = dir ? (T_ - 1 - t) : t;
    floatx4 acc[4] = {bias[0], bias[1], bias[2], bias[3]};

    // input projection (independent of h) — off the critical path
#pragma unroll
    for (int c = 0; c < 5; ++c) {
#pragma unroll
      for (int tl = 0; tl < 4; ++tl)
        acc[tl] = __builtin_amdgcn_mfma_f32_16x16x32_bf16(wif[tl][c], xf[c], acc[tl], 0, 0, 0);
    }
    // prefetch next step's x
    if (t + 1 < T_) {
      const int xtn = dir ? (T_ - 2 - t) : (t + 1);
      const bf16* xr = xp + (size_t)(xtn * B_ + btile * 16 + m) * DINP + q * 8;
#pragma unroll
      for (int c = 0; c < 5; ++c) xf[c] = *(const bf16x8*)(xr + c * 32);
    }

    if (t > 0) {
      const int tp = t - 1;
      const int p  = tp & 1;
      const unsigned expTag = (unsigned)tp;
      const size_t page = (size_t)(((tp & 3) * 8) + g) * 4096;
      const int q1 = (qtr + 1) & 3, q2 = (qtr + 2) & 3, q3 = (qtr + 3) & 3;
      const unsigned* p0 = ring + page + (size_t)(q1 * 1024 + mm * 64 + j4);
      const unsigned* p1 = ring + page + (size_t)(q2 * 1024 + mm * 64 + j4);
      const unsigned* p2 = ring + page + (size_t)(q3 * 1024 + mm * 64 + j4);

      int4v d0, d1, d2;
      for (;;) {
        asm volatile(
          "global_load_dwordx4 %0, %[a0], off sc0 sc1\n\t"
          "global_load_dwordx4 %1, %[a1], off sc0 sc1\n\t"
          "global_load_dwordx4 %2, %[a2], off sc0 sc1\n\t"
          "s_waitcnt vmcnt(0)"
          : "=v"(d0), "=v"(d1), "=v"(d2)
          : [a0] "v"(p0), [a1] "v"(p1), [a2] "v"(p2)
          : "memory");
        unsigned dev =
            (((unsigned)d0[0] >> 16) ^ expTag) | (((unsigned)d0[1] >> 16) ^ expTag) |
            (((unsigned)d0[2] >> 16) ^ expTag) | (((unsigned)d0[3] >> 16) ^ expTag) |
            (((unsigned)d1[0] >> 16) ^ expTag) | (((unsigned)d1[1] >> 16) ^ expTag) |
            (((unsigned)d1[2] >> 16) ^ expTag) | (((unsigned)d1[3] >> 16) ^ expTag) |
            (((unsigned)d2[0] >> 16) ^ expTag) | (((unsigned)d2[1] >> 16) ^ expTag) |
            (((unsigned)d2[2] >> 16) ^ expTag) | (((unsigned)d2[3] >> 16) ^ expTag);
        if (__all((int)(dev == 0u))) break;
        __builtin_amdgcn_s_sleep(1);   // throttle: don't flood the coherence point
      }

      // unscramble partner quarters into LDS buffer p
      {
        unsigned short* hb = h_su + (size_t)(p * 16 + mm) * 264;
#pragma unroll
        for (int i = 0; i < 4; ++i) hb[q1 * 64 + hid0 + i * 4] = (unsigned short)((unsigned)d0[i] & 0xFFFFu);
#pragma unroll
        for (int i = 0; i < 4; ++i) hb[q2 * 64 + hid0 + i * 4] = (unsigned short)((unsigned)d1[i] & 0xFFFFu);
#pragma unroll
        for (int i = 0; i < 4; ++i) hb[q3 * 64 + hid0 + i * 4] = (unsigned short)((unsigned)d2[i] & 0xFFFFu);
      }
      __syncthreads();   // own quarter was written at end of previous iteration

      // Whh MFMAs: 8 K-chunks from LDS buffer p
      const bf16* hrow = (const bf16*)(h_su + (size_t)(p * 16 + m) * 264);
#pragma unroll
      for (int c = 0; c < 8; ++c) {
        bf16x8 hfr = *(const bf16x8*)(hrow + c * 32 + q * 8);
#pragma unroll
        for (int tl = 0; tl < 4; ++tl)
          acc[tl] = __builtin_amdgcn_mfma_f32_16x16x32_bf16(wf[tl][c], hfr, acc[tl], 0, 0, 0);
      }
    }

    // in-lane cell update: reg0=i reg1=f reg2=g reg3=o for (hid = qtr*64+w*16+tl*4+q, b = btile*16+m)
    unsigned short hu[4];
#pragma unroll
    for (int tl = 0; tl < 4; ++tl) {
      float pi = acc[tl][0], pf = acc[tl][1], pg = acc[tl][2], po = acc[tl][3];
      float ig = 1.f / (1.f + __expf(-pi));
      float fg = 1.f / (1.f + __expf(-pf));
      float og = 1.f / (1.f + __expf(-po));
      float gcl = fminf(fmaxf(pg, -15.f), 15.f);
      float e2  = __expf(2.f * gcl);
      float gg  = (e2 - 1.f) / (e2 + 1.f);
      float c   = fg * cst[tl] + ig * gg;
      cst[tl]   = c;
      float ccl = fminf(fmaxf(c, -15.f), 15.f);
      float ec  = __expf(2.f * ccl);
      float hv  = og * ((ec - 1.f) / (ec + 1.f));
      bf16 hb = (bf16)hv;
      hu[tl] = __builtin_bit_cast(unsigned short, hb);
    }

    // publish FIRST: one tagged dwordx4 per lane into ring page [t&3][g][qtr][m][j]
    {
      const unsigned tagv = ((unsigned)t) << 16;
      unsigned* pp = ring + (size_t)(((t & 3) * 8) + g) * 4096
                   + (size_t)(qtr * 1024 + m * 64 + w * 16 + q * 4);
      int4v dv;
      dv[0] = (int)(tagv | (unsigned)hu[0]);
      dv[1] = (int)(tagv | (unsigned)hu[1]);
      dv[2] = (int)(tagv | (unsigned)hu[2]);
      dv[3] = (int)(tagv | (unsigned)hu[3]);
      asm volatile("global_store_dwordx4 %[a], %[d], off sc0 sc1"
                   :: [a] "v"(pp), [d] "v"(dv) : "memory");
    }

    // plain cached bf16 stores for k_fc (visible at kernel boundary)
    {
      const size_t obase = ((hb_g + xt) * 16 + m) * 128 + (size_t)(qtr * 32 + w * 8);
#pragma unroll
      for (int tl = 0; tl < 4; ++tl) {
        int ov = __shfl_xor((int)(unsigned)hu[tl], 16);
        if ((q & 1) == 0) {
          unsigned dw = (unsigned)hu[tl] | ((unsigned)ov << 16);
          hseq_dw[obase + tl * 2 + (q >> 1)] = dw;
        }
      }
    }

    // own quarter into LDS buffer (t&1) for next step
    {
      unsigned short* hb = h_su + (size_t)((t & 1) * 16 + m) * 264;
#pragma unroll
      for (int tl = 0; tl < 4; ++tl)
        hb[qtr * 64 + w * 16 + tl * 4 + q] = hu[tl];
    }
  }
}

// ---------------- FC epilogue ----------------
// one block per t; hseq layout [g=dir*4+btile][xt][m][hid 256] bf16
__global__ __launch_bounds__(512) void k_fc(const bf16* __restrict__ hbuf,
                                            const float* __restrict__ fcw,
                                            const float* __restrict__ fcb,
                                            float* __restrict__ out)
{
  __shared__ float wsm[5 * 512];
  __shared__ unsigned short hl[64 * 258];      // [b][hid 256 pad 258]
  const int tid = threadIdx.x;
  const int t   = blockIdx.x;
  for (int i = tid; i < 2560; i += 512) wsm[i] = fcw[i];
  const int o = tid / 64, b = tid & 63;
  float acc = 0.f;
  for (int dirc = 0; dirc < 2; ++dirc) {
    __syncthreads();
    for (int i = tid; i < 8192; i += 512) {
      int bb = i >> 7, dd = i & 127;
      int gg = dirc * 4 + (bb >> 4), mmx = bb & 15;
      ((unsigned*)hl)[bb * 129 + dd] =
          ((const unsigned*)hbuf)[((size_t)(gg * T_ + t) * 16 + mmx) * 128 + dd];
    }
    __syncthreads();
    if (tid < 320) {
      const float* wr = &wsm[o * 512 + dirc * 256];
      const unsigned short* hr = &hl[b * 258];
      float a = 0.f;
#pragma unroll 8
      for (int h = 0; h < 256; ++h) {
        unsigned u = ((unsigned)hr[h]) << 16;
        a += wr[h] * __builtin_bit_cast(float, u);
      }
      acc += a;
    }
  }
  if (tid < 320) out[((size_t)b * T_ + t) * 5 + o] = acc + fcb[o];
}

// ---------------- launcher ----------------
extern "C" void kernel_launch(void* const* d_in, const int* in_sizes, int n_in,
                              void* d_out, int out_size, void* d_ws, size_t ws_size,
                              hipStream_t stream) {
  const float* x    = (const float*)d_in[0];
  const float* wihf = (const float*)d_in[1];
  const float* whhf = (const float*)d_in[2];
  const float* bihf = (const float*)d_in[3];
  const float* bhhf = (const float*)d_in[4];
  const float* wihb = (const float*)d_in[5];
  const float* whhb = (const float*)d_in[6];
  const float* bihb = (const float*)d_in[7];
  const float* bhhb = (const float*)d_in[8];
  const float* fcw  = (const float*)d_in[9];
  const float* fcb  = (const float*)d_in[10];
  float* out = (float*)d_out;

  char* ws = (char*)d_ws;
  bf16*     xp   = (bf16*)(ws + 0);            // 20,971,520 B
  bf16*     whhp = (bf16*)(ws + 20971520);     //  1,048,576 B
  bf16*     wihp = (bf16*)(ws + 22020096);     //    655,360 B
  float*    bsum = (float*)(ws + 22675456);    //      8,192 B
  unsigned* ring = (unsigned*)(ws + 22683648); //    524,288 B (poison tag 0xAAAA != any t; no memset)
  bf16*     hseq = (bf16*)(ws + 23207936);     // 67,108,864 B  [g][xt][m][hid]
  (void)in_sizes; (void)n_in; (void)out_size; (void)ws_size;

  k_pack_x   <<<4096, 256, 0, stream>>>(x, xp);
  k_pack_whh <<<1024, 256, 0, stream>>>(whhf, whhb, whhp);
  k_pack_wih <<<640,  256, 0, stream>>>(wihf, wihb, wihp);
  k_pack_bias<<<8,    256, 0, stream>>>(bihf, bhhf, bihb, bhhb, bsum);
  k_lstm     <<<32,   256, 0, stream>>>(xp, whhp, wihp, bsum, hseq, ring);
  k_fc       <<<1024, 512, 0, stream>>>(hseq, fcw, fcb, out);
}